// Round 1
// baseline (287.703 us; speedup 1.0000x reference)
//
#include <hip/hip_runtime.h>
#include <cstdint>

#define M_DIM 65536
#define N_DIM 512
#define K_DIM 512
#define BM 128
#define BN 128
#define BK 32

typedef float f32x4 __attribute__((ext_vector_type(4)));
typedef __bf16 bf16x8 __attribute__((ext_vector_type(8)));
typedef unsigned short us8 __attribute__((ext_vector_type(8)));

__device__ __forceinline__ unsigned short f2bf(float f) {
  unsigned int u = __builtin_bit_cast(unsigned int, f);
  u += 0x7fffu + ((u >> 16) & 1u);  // round-to-nearest-even
  return (unsigned short)(u >> 16);
}

__device__ __forceinline__ void async_copy16(const void* gptr, void* ldsptr) {
  __builtin_amdgcn_global_load_lds(
      (const __attribute__((address_space(1))) void*)gptr,
      (__attribute__((address_space(3))) void*)ldsptr, 16, 0, 0);
}

// ---------------------------------------------------------------------------
// Prep: WCT[(o*8+k)*512 + n*8+i] = bf16( sum_j nan0(weight[o,n,j]*rs[o]*cs[n]) * C[i,j,k] )
//       bias2[o*8+k] = bias[o,k] + (k==0)*bias_shift[o]
// ---------------------------------------------------------------------------
__global__ void clifford_prep(const float* __restrict__ weight,
                              const float* __restrict__ bias,
                              const float* __restrict__ row_scale,
                              const float* __restrict__ col_scale,
                              const float* __restrict__ bias_shift,
                              unsigned short* __restrict__ WCT,
                              float* __restrict__ bias2) {
  const int t = blockIdx.x * 256 + threadIdx.x;
  if (t < 512) {
    const int o = t >> 3, k = t & 7;
    bias2[t] = bias[t] + (k == 0 ? bias_shift[o] : 0.0f);
  }
  if (t >= 64 * 64) return;
  const int o = t >> 6, n = t & 63;
  const float rs = row_scale[o], cs = col_scale[n];
  float w[8];
#pragma unroll
  for (int j = 0; j < 8; ++j) {
    float v = weight[(size_t)t * 8 + j] * rs * cs;
    w[j] = (v != v) ? 0.0f : v;  // nan_to_num
  }
  // Cl(3,0) structure constants: (i, j, k, sign), grouped by k
  constexpr int TI[64] = {0,1,2,3,4,5,6,7, 0,1,2,4,3,5,6,7, 0,2,1,4,3,6,5,7,
                          0,3,1,5,2,6,4,7, 0,4,1,2,3,7,5,6, 0,5,1,3,2,7,4,6,
                          0,6,2,3,1,7,4,5, 0,7,1,6,2,5,3,4};
  constexpr int TJ[64] = {0,1,2,3,4,5,6,7, 1,0,4,2,5,3,7,6, 2,0,4,1,6,3,7,5,
                          3,0,5,1,6,2,7,4, 4,0,2,1,7,3,6,5, 5,0,3,1,7,2,6,4,
                          6,0,3,2,7,1,5,4, 7,0,6,1,5,2,4,3};
  constexpr int TK[64] = {0,0,0,0,0,0,0,0, 1,1,1,1,1,1,1,1, 2,2,2,2,2,2,2,2,
                          3,3,3,3,3,3,3,3, 4,4,4,4,4,4,4,4, 5,5,5,5,5,5,5,5,
                          6,6,6,6,6,6,6,6, 7,7,7,7,7,7,7,7};
  constexpr float TS[64] = {1,1,1,1,-1,-1,-1,-1, 1,1,-1,1,-1,1,-1,-1, 1,1,1,-1,-1,1,1,1,
                            1,1,1,-1,1,-1,-1,-1, 1,1,1,-1,1,1,-1,1,  1,1,1,-1,-1,-1,1,-1,
                            1,1,1,-1,1,1,-1,1,   1,1,1,1,-1,-1,1,1};
  float wc[8][8];
#pragma unroll
  for (int i = 0; i < 8; ++i)
#pragma unroll
    for (int k = 0; k < 8; ++k) wc[i][k] = 0.0f;
#pragma unroll
  for (int e = 0; e < 64; ++e) wc[TI[e]][TK[e]] += TS[e] * w[TJ[e]];
#pragma unroll
  for (int k = 0; k < 8; ++k)
#pragma unroll
    for (int i = 0; i < 8; ++i)
      WCT[(size_t)(o * 8 + k) * K_DIM + (n * 8 + i)] = f2bf(wc[i][k]);
}

// ---------------------------------------------------------------------------
// GEMM: out[M,N] = x[M,K] * WCT^T  (+ bias2 epilogue)
// m97 structure: 128x128 tile, BK=32, 4 waves (2x2), 16x16x32 bf16 MFMA, 4x4
// frags/wave, global_load_lds width-16 staging. A is fp32 in LDS with XOR
// swizzle on 16B groups (phys = logical ^ (row&7)); cvt to bf16 at frag load.
// ---------------------------------------------------------------------------
__global__ __launch_bounds__(256) void clifford_gemm(
    const float* __restrict__ x, const unsigned short* __restrict__ WCT,
    const float* __restrict__ bias2, float* __restrict__ out) {
  __shared__ __align__(16) float As[BM * BK];           // 16 KB, swizzled
  __shared__ __align__(16) unsigned short Bs[BN * BK];  // 8 KB, [n][k]

  const int tid = threadIdx.x;
  const int lane = tid & 63;
  const int wv = tid >> 6;

  const int n0 = (blockIdx.x & 3) * BN;
  const size_t m0 = (size_t)(blockIdx.x >> 2) * BM;

  // staging geometry: A: 8 lanes/row (32 floats), 8 rows/issue, 4 issues/wave
  const int a_row = lane >> 3;               // row within 8-row slab
  const int a_grp = (lane & 7) ^ a_row;      // swizzled logical 16B-group
  // B: 4 lanes/row (32 bf16), 16 rows/issue, 2 issues/wave
  const int b_row = lane >> 2;
  const int b_grp = lane & 3;

  const float* xg = x + (m0 + (size_t)wv * 32) * K_DIM;
  float* AsW = &As[(wv * 32) * BK];
  unsigned short* BsW = &Bs[(wv * 32) * BK];

  // fragment geometry (16x16x32: A[m=lane&15][k=(lane>>4)*8+j])
  const int wm = (wv & 1) * 64;
  const int wn = (wv >> 1) * 64;
  const int lm = lane & 15;
  const int kg = lane >> 4;                  // 0..3
  const int p0 = (kg << 1) ^ (lm & 7);       // physical 16B-group of k-low half

  const f32x4 zero = {0.f, 0.f, 0.f, 0.f};
  f32x4 acc[4][4];
#pragma unroll
  for (int i = 0; i < 4; ++i)
#pragma unroll
    for (int j = 0; j < 4; ++j) acc[i][j] = zero;

  for (int ks = 0; ks < K_DIM / BK; ++ks) {
    const int kc = ks * BK;
    __syncthreads();
#pragma unroll
    for (int tslab = 0; tslab < 4; ++tslab) {
      const float* g = xg + (size_t)(tslab * 8 + a_row) * K_DIM + kc + a_grp * 4;
      async_copy16(g, AsW + tslab * 8 * BK);
    }
#pragma unroll
    for (int tslab = 0; tslab < 2; ++tslab) {
      const unsigned short* g =
          WCT + (size_t)(n0 + wv * 32 + tslab * 16 + b_row) * K_DIM + kc + b_grp * 8;
      async_copy16(g, BsW + tslab * 16 * BK);
    }
    __syncthreads();  // compiler emits vmcnt(0) drain -> LDS tiles ready

    bf16x8 af[4], bfr[4];
#pragma unroll
    for (int mi = 0; mi < 4; ++mi) {
      const float* base = &As[(wm + mi * 16 + lm) * BK];
      f32x4 lo = *(const f32x4*)(base + p0 * 4);
      f32x4 hi = *(const f32x4*)(base + (p0 ^ 1) * 4);
      union { bf16x8 v; unsigned short u[8]; } cv;
#pragma unroll
      for (int j = 0; j < 4; ++j) {
        cv.u[j] = f2bf(lo[j]);
        cv.u[4 + j] = f2bf(hi[j]);
      }
      af[mi] = cv.v;
    }
#pragma unroll
    for (int ni = 0; ni < 4; ++ni) {
      us8 raw = *(const us8*)&Bs[(wn + ni * 16 + lm) * BK + kg * 8];
      bfr[ni] = __builtin_bit_cast(bf16x8, raw);
    }
#pragma unroll
    for (int mi = 0; mi < 4; ++mi)
#pragma unroll
      for (int ni = 0; ni < 4; ++ni)
        acc[mi][ni] = __builtin_amdgcn_mfma_f32_16x16x32_bf16(af[mi], bfr[ni],
                                                              acc[mi][ni], 0, 0, 0);
  }

  // epilogue: C/D layout col=lane&15, row=(lane>>4)*4+reg
#pragma unroll
  for (int ni = 0; ni < 4; ++ni) {
    const int nn = n0 + wn + ni * 16 + lm;
    const float b2 = bias2[nn];
#pragma unroll
    for (int mi = 0; mi < 4; ++mi) {
#pragma unroll
      for (int r = 0; r < 4; ++r) {
        const size_t mm = m0 + wm + mi * 16 + kg * 4 + r;
        out[mm * N_DIM + nn] = acc[mi][ni][r] + b2;
      }
    }
  }
}

extern "C" void kernel_launch(void* const* d_in, const int* in_sizes, int n_in,
                              void* d_out, int out_size, void* d_ws, size_t ws_size,
                              hipStream_t stream) {
  const float* x          = (const float*)d_in[0];
  const float* weight     = (const float*)d_in[1];
  const float* bias       = (const float*)d_in[2];
  const float* row_scale  = (const float*)d_in[3];
  const float* col_scale  = (const float*)d_in[4];
  const float* bias_shift = (const float*)d_in[5];

  unsigned short* WCT = (unsigned short*)d_ws;                       // 512*512*2 B
  float* bias2 = (float*)((char*)d_ws + (size_t)N_DIM * K_DIM * 2);  // +2 KB

  clifford_prep<<<16, 256, 0, stream>>>(weight, bias, row_scale, col_scale,
                                        bias_shift, WCT, bias2);
  clifford_gemm<<<(M_DIM / BM) * (N_DIM / BN), 256, 0, stream>>>(
      x, WCT, bias2, (float*)d_out);
}

// Round 2
// 280.364 us; speedup vs baseline: 1.0262x; 1.0262x over previous
//
#include <hip/hip_runtime.h>
#include <cstdint>

#define M_DIM 65536
#define N_DIM 512
#define K_DIM 512
#define BM 128
#define BN 128
#define BK 32
#define KSTEPS (K_DIM / BK)

typedef float f32x4 __attribute__((ext_vector_type(4)));
typedef __bf16 bf16x8 __attribute__((ext_vector_type(8)));
typedef unsigned short us8 __attribute__((ext_vector_type(8)));

__device__ __forceinline__ unsigned short f2bf(float f) {
  unsigned int u = __builtin_bit_cast(unsigned int, f);
  u += 0x7fffu + ((u >> 16) & 1u);  // round-to-nearest-even
  return (unsigned short)(u >> 16);
}

__device__ __forceinline__ void async_copy16(const void* gptr, void* ldsptr) {
  __builtin_amdgcn_global_load_lds(
      (const __attribute__((address_space(1))) void*)gptr,
      (__attribute__((address_space(3))) void*)ldsptr, 16, 0, 0);
}

// ---------------------------------------------------------------------------
// Prep: WCT[(o*8+k)*512 + n*8+i] = bf16( sum_j nan0(weight[o,n,j]*rs[o]*cs[n]) * C[i,j,k] )
//       bias2[o*8+k] = bias[o,k] + (k==0)*bias_shift[o]
// ---------------------------------------------------------------------------
__global__ void clifford_prep(const float* __restrict__ weight,
                              const float* __restrict__ bias,
                              const float* __restrict__ row_scale,
                              const float* __restrict__ col_scale,
                              const float* __restrict__ bias_shift,
                              unsigned short* __restrict__ WCT,
                              float* __restrict__ bias2) {
  const int t = blockIdx.x * 256 + threadIdx.x;
  if (t < 512) {
    const int o = t >> 3, k = t & 7;
    bias2[t] = bias[t] + (k == 0 ? bias_shift[o] : 0.0f);
  }
  if (t >= 64 * 64) return;
  const int o = t >> 6, n = t & 63;
  const float rs = row_scale[o], cs = col_scale[n];
  float w[8];
#pragma unroll
  for (int j = 0; j < 8; ++j) {
    float v = weight[(size_t)t * 8 + j] * rs * cs;
    w[j] = (v != v) ? 0.0f : v;  // nan_to_num
  }
  constexpr int TI[64] = {0,1,2,3,4,5,6,7, 0,1,2,4,3,5,6,7, 0,2,1,4,3,6,5,7,
                          0,3,1,5,2,6,4,7, 0,4,1,2,3,7,5,6, 0,5,1,3,2,7,4,6,
                          0,6,2,3,1,7,4,5, 0,7,1,6,2,5,3,4};
  constexpr int TJ[64] = {0,1,2,3,4,5,6,7, 1,0,4,2,5,3,7,6, 2,0,4,1,6,3,7,5,
                          3,0,5,1,6,2,7,4, 4,0,2,1,7,3,6,5, 5,0,3,1,7,2,6,4,
                          6,0,3,2,7,1,5,4, 7,0,6,1,5,2,4,3};
  constexpr int TK[64] = {0,0,0,0,0,0,0,0, 1,1,1,1,1,1,1,1, 2,2,2,2,2,2,2,2,
                          3,3,3,3,3,3,3,3, 4,4,4,4,4,4,4,4, 5,5,5,5,5,5,5,5,
                          6,6,6,6,6,6,6,6, 7,7,7,7,7,7,7,7};
  constexpr float TS[64] = {1,1,1,1,-1,-1,-1,-1, 1,1,-1,1,-1,1,-1,-1, 1,1,1,-1,-1,1,1,1,
                            1,1,1,-1,1,-1,-1,-1, 1,1,1,-1,1,1,-1,1,  1,1,1,-1,-1,-1,1,-1,
                            1,1,1,-1,1,1,-1,1,   1,1,1,1,-1,-1,1,1};
  float wc[8][8];
#pragma unroll
  for (int i = 0; i < 8; ++i)
#pragma unroll
    for (int k = 0; k < 8; ++k) wc[i][k] = 0.0f;
#pragma unroll
  for (int e = 0; e < 64; ++e) wc[TI[e]][TK[e]] += TS[e] * w[TJ[e]];
#pragma unroll
  for (int k = 0; k < 8; ++k)
#pragma unroll
    for (int i = 0; i < 8; ++i)
      WCT[(size_t)(o * 8 + k) * K_DIM + (n * 8 + i)] = f2bf(wc[i][k]);
}

// ---------------------------------------------------------------------------
// GEMM: out[M,N] = x[M,K] * WCT^T  (+ bias2 epilogue)
// Software-pipelined: A staged global->VGPR->cvt bf16->ds_write (dbuf),
// B staged via async global_load_lds (dbuf, L2-resident weights). One
// __syncthreads per k-step. XCD swizzle: the 4 n-tiles of an m-tile are
// blockIdx siblings at stride 8 -> same XCD -> x fetched from HBM once.
// ---------------------------------------------------------------------------
__global__ __launch_bounds__(256) void clifford_gemm(
    const float* __restrict__ x, const unsigned short* __restrict__ WCT,
    const float* __restrict__ bias2, float* __restrict__ out) {
  __shared__ __align__(16) unsigned short As[2][BM * BK];  // 2 x 8 KB bf16
  __shared__ __align__(16) unsigned short Bs[2][BN * BK];  // 2 x 8 KB bf16

  const int tid = threadIdx.x;
  const int lane = tid & 63;
  const int wv = tid >> 6;

  // XCD swizzle: grid = 2048 = 64 groups x 32. Within a group of 32 ids,
  // r&7 = XCD (round-robin dispatch), r>>3 = n-tile -> 4 n-tiles of one
  // m-tile land on the same XCD.
  const int bid = blockIdx.x;
  const int grp = bid >> 5, r = bid & 31;
  const size_t m0 = (size_t)(grp * 8 + (r & 7)) * BM;
  const int n0 = (r >> 3) * BN;

  // A register staging: thread t loads 16 consecutive floats of row t>>1
  const int s_row = tid >> 1;
  const int s_half = tid & 1;
  const float* ag = x + (m0 + s_row) * (size_t)K_DIM + s_half * 16;

  // B async staging: 4 lanes/row (32 bf16), 16 rows/issue, 2 issues/wave
  const int b_row = lane >> 2;
  const int b_grp = lane & 3;

  // fragment geometry (16x16x32: A[m=lane&15][k=(lane>>4)*8+j])
  const int wm = (wv & 1) * 64;
  const int wn = (wv >> 1) * 64;
  const int lm = lane & 15;
  const int kg = lane >> 4;  // 0..3

  f32x4 ar[4];

  const f32x4 zero = {0.f, 0.f, 0.f, 0.f};
  f32x4 acc[4][4];
#pragma unroll
  for (int i = 0; i < 4; ++i)
#pragma unroll
    for (int j = 0; j < 4; ++j) acc[i][j] = zero;

  auto stageB = [&](int buf, int kc) {
    unsigned short* dst = &Bs[buf][(wv * 32) * BK];
#pragma unroll
    for (int ts = 0; ts < 2; ++ts) {
      const unsigned short* g =
          WCT + (size_t)(n0 + wv * 32 + ts * 16 + b_row) * K_DIM + kc + b_grp * 8;
      async_copy16(g, dst + ts * 16 * BK);
    }
  };
  auto loadA = [&](int kc) {
#pragma unroll
    for (int j = 0; j < 4; ++j) ar[j] = *(const f32x4*)(ag + kc + j * 4);
  };
  auto writeA = [&](int buf) {
    union { us8 v; unsigned short u[8]; } p0, p1;
#pragma unroll
    for (int j = 0; j < 4; ++j) {
      p0.u[j] = f2bf(ar[0][j]);
      p0.u[4 + j] = f2bf(ar[1][j]);
      p1.u[j] = f2bf(ar[2][j]);
      p1.u[4 + j] = f2bf(ar[3][j]);
    }
    unsigned short* dst = &As[buf][s_row * BK + s_half * 16];
    *(us8*)dst = p0.v;
    *(us8*)(dst + 8) = p1.v;
  };

  // prologue: stage k-step 0
  stageB(0, 0);
  loadA(0);
  writeA(0);
  __syncthreads();  // drains ds_write (lgkm) + B async (vmcnt)

  int buf = 0;
  for (int ks = 0; ks < KSTEPS; ++ks) {
    if (ks < KSTEPS - 1) {
      stageB(buf ^ 1, (ks + 1) * BK);  // safe: everyone passed last barrier
      loadA((ks + 1) * BK);            // in flight during MFMA below
    }
    bf16x8 af[4], bfr[4];
#pragma unroll
    for (int mi = 0; mi < 4; ++mi)
      af[mi] = __builtin_bit_cast(
          bf16x8, *(const us8*)&As[buf][(wm + mi * 16 + lm) * BK + kg * 8]);
#pragma unroll
    for (int ni = 0; ni < 4; ++ni)
      bfr[ni] = __builtin_bit_cast(
          bf16x8, *(const us8*)&Bs[buf][(wn + ni * 16 + lm) * BK + kg * 8]);
#pragma unroll
    for (int mi = 0; mi < 4; ++mi)
#pragma unroll
      for (int ni = 0; ni < 4; ++ni)
        acc[mi][ni] = __builtin_amdgcn_mfma_f32_16x16x32_bf16(af[mi], bfr[ni],
                                                              acc[mi][ni], 0, 0, 0);
    if (ks < KSTEPS - 1) {
      writeA(buf ^ 1);   // compiler waits vmcnt on ar[] here, not at barrier
      __syncthreads();   // next iter reads buf^1; also covers B async arrival
      buf ^= 1;
    }
  }

  // epilogue: C/D layout col=lane&15 (n), row=(lane>>4)*4+reg (m)
#pragma unroll
  for (int ni = 0; ni < 4; ++ni) {
    const int nn = n0 + wn + ni * 16 + lm;
    const float b2 = bias2[nn];
#pragma unroll
    for (int mi = 0; mi < 4; ++mi) {
#pragma unroll
      for (int rr = 0; rr < 4; ++rr) {
        const size_t mm = m0 + wm + mi * 16 + kg * 4 + rr;
        out[mm * N_DIM + nn] = acc[mi][ni][rr] + b2;
      }
    }
  }
}

extern "C" void kernel_launch(void* const* d_in, const int* in_sizes, int n_in,
                              void* d_out, int out_size, void* d_ws, size_t ws_size,
                              hipStream_t stream) {
  const float* x          = (const float*)d_in[0];
  const float* weight     = (const float*)d_in[1];
  const float* bias       = (const float*)d_in[2];
  const float* row_scale  = (const float*)d_in[3];
  const float* col_scale  = (const float*)d_in[4];
  const float* bias_shift = (const float*)d_in[5];

  unsigned short* WCT = (unsigned short*)d_ws;                       // 512*512*2 B
  float* bias2 = (float*)((char*)d_ws + (size_t)N_DIM * K_DIM * 2);  // +2 KB

  clifford_prep<<<16, 256, 0, stream>>>(weight, bias, row_scale, col_scale,
                                        bias_shift, WCT, bias2);
  clifford_gemm<<<(M_DIM / BM) * (N_DIM / BN), 256, 0, stream>>>(
      x, WCT, bias2, (float*)d_out);
}